// Round 15
// baseline (287.962 us; speedup 1.0000x reference)
//
#include <hip/hip_runtime.h>

typedef unsigned short u16;
typedef short bh8 __attribute__((ext_vector_type(8)));
typedef short bh4 __attribute__((ext_vector_type(4)));
typedef float f4 __attribute__((ext_vector_type(4)));
typedef u16 u16x4 __attribute__((ext_vector_type(4)));

// ---------- helpers ----------
__device__ __forceinline__ u16 f2bf(float f) {
  union { float f; unsigned u; } v; v.f = f;
  unsigned u = v.u;
  return (u16)((u + 0x7fffu + ((u >> 16) & 1u)) >> 16);   // RNE, finite inputs
}
__device__ __forceinline__ float bf2f(u16 h) {
  union { unsigned u; float f; } v; v.u = ((unsigned)h) << 16;
  return v.f;
}
__device__ __forceinline__ float fast_exp2(float x) {
#if __has_builtin(__builtin_amdgcn_exp2f)
  return __builtin_amdgcn_exp2f(x);
#else
  float r; asm("v_exp_f32 %0, %1" : "=v"(r) : "v"(x)); return r;
#endif
}
__device__ __forceinline__ unsigned cvt_pk_bf16(float lo, float hi) {
  unsigned r;
  asm("v_cvt_pk_bf16_f32 %0, %1, %2" : "=v"(r) : "v"(lo), "v"(hi));
  return r;
}
__device__ __forceinline__ void gll16(const void* src, void* dst) {
  __builtin_amdgcn_global_load_lds((const __attribute__((address_space(1))) void*)src,
                                   (__attribute__((address_space(3))) void*)dst,
                                   16, 0, 0);
}

// ---------- fused f32 -> bf16 convert of all 5 tensors (contiguous ws dst) ----------
__global__ __launch_bounds__(256) void k_cvt_all(const float* __restrict__ x,
                                                 const float* __restrict__ wq,
                                                 const float* __restrict__ wk,
                                                 const float* __restrict__ wv,
                                                 const float* __restrict__ wo,
                                                 u16* __restrict__ dst) {
  const size_t n = 5767168;   // total float4 count
  for (size_t idx = (size_t)blockIdx.x * 256 + threadIdx.x; idx < n; idx += 4096ull * 256) {
    const float* src; size_t off;
    if (idx < 1048576)       { src = x;  off = idx; }
    else if (idx < 3145728)  { src = wq; off = idx - 1048576; }
    else if (idx < 3407872)  { src = wk; off = idx - 3145728; }
    else if (idx < 3670016)  { src = wv; off = idx - 3407872; }
    else                     { src = wo; off = idx - 3670016; }
    f4 v = *(const f4*)(src + off * 4);
    u16x4 o;
    o.x = f2bf(v[0]); o.y = f2bf(v[1]); o.z = f2bf(v[2]); o.w = f2bf(v[3]);
    *(u16x4*)(dst + idx * 4) = o;
  }
}

// ---------- NT GEMM, round-8 structure: straight-line main loop + hardcoded tail ----------
// C[M,N] = A[M,K] * B[N,K]^T.  128xBN tile (BN = NFR*32), BK=32, 4 waves (2x2).
// 3 LDS buffers, compile-time vmcnt (8/4/0 for NFR=4; 6/3/0 for NFR=2).
// XCD-contiguous 1D grid.  FUSED: bn<NB1 -> Q (C1); else KV: local bn<nbK -> K
// cols of C2; bn>=nbK -> V, written TRANSPOSED + chunk-permuted to Cv.
template<int K, bool OUTF32, int NFR, bool FUSED>
__global__ __launch_bounds__(256) void k_gemm(const u16* __restrict__ A,
                                              const u16* __restrict__ B1,
                                              const u16* __restrict__ B2,
                                              void* __restrict__ C1,
                                              void* __restrict__ C2,
                                              u16* __restrict__ Cv,
                                              int N1, int N2, int NB1, int npx,
                                              int nbK) {
  constexpr int BN = NFR * 32;
  constexpr int nk = K / 32;
  constexpr int LBB = BN / 64;                 // B-staging loops (A has 2)
  __shared__ u16 As[3][128 * 32];
  __shared__ u16 Bs[3][BN * 32];
  const int t = threadIdx.x;
  const int lane = t & 63;
  const int w = t >> 6, wm = w >> 1, wn = w & 1;
  const int g = lane >> 4, r16 = lane & 15;
  const int bb = blockIdx.x;
  const int gl = (bb & 7) * npx + (bb >> 3);   // XCD-contiguous mapping
  const int bm = gl & 15;
  int bn = gl >> 4;

  const u16* B; void* C; int N; bool vpath = false;
  if (!FUSED || bn < NB1) { B = B1; C = C1; N = N1; }
  else { bn -= NB1; B = B2; C = C2; N = N2; vpath = (bn >= nbK); }
  B += (size_t)bn * BN * K;
  const u16* Ab = A + (size_t)bm * 128 * K;

  f4 acc[4][NFR] = {};

  auto STAGE = [&](int kk, int bi) {
    const int k0 = kk * 32;
#pragma unroll
    for (int i2 = 0; i2 < 2; ++i2) {
      const int s = t + 256 * i2;
      const int row = s >> 2, slot = s & 3;
      gll16(Ab + (size_t)row * K + k0 + ((slot ^ (row & 3)) * 8), As[bi] + s * 8);
    }
#pragma unroll
    for (int i2 = 0; i2 < LBB; ++i2) {
      const int s = t + 256 * i2;
      const int col = s >> 2, slot = s & 3;
      gll16(B + (size_t)col * K + k0 + ((slot ^ (col & 3)) * 8), Bs[bi] + s * 8);
    }
  };
  auto COMP = [&](int bi) {
    bh8 af[4], bfr[NFR];
    const int x4 = g ^ (r16 & 3);              // row&3 == col&3 == r16&3
#pragma unroll
    for (int m = 0; m < 4; ++m)
      af[m] = *(const bh8*)&As[bi][((wm * 64 + m * 16 + r16) * 4 + x4) * 8];
#pragma unroll
    for (int n = 0; n < NFR; ++n)
      bfr[n] = *(const bh8*)&Bs[bi][((wn * 16 * NFR + n * 16 + r16) * 4 + x4) * 8];
    __builtin_amdgcn_s_setprio(1);
#pragma unroll
    for (int m = 0; m < 4; ++m)
#pragma unroll
      for (int n = 0; n < NFR; ++n)
        acc[m][n] = __builtin_amdgcn_mfma_f32_16x16x32_bf16(af[m], bfr[n], acc[m][n], 0, 0, 0);
    __builtin_amdgcn_s_setprio(0);
  };

  STAGE(0, 0);
  STAGE(1, 1);

  int bi = 0;
  for (int k = 0; k < nk - 2; ++k) {
    int st = bi + 2; if (st >= 3) st -= 3;
    STAGE(k + 2, st);
    if constexpr (NFR == 4) asm volatile("s_waitcnt vmcnt(8)" ::: "memory");
    else                    asm volatile("s_waitcnt vmcnt(6)" ::: "memory");
    __builtin_amdgcn_s_barrier();
    __builtin_amdgcn_sched_barrier(0);
    COMP(bi);
    asm volatile("s_waitcnt lgkmcnt(0)" ::: "memory");
    __builtin_amdgcn_s_barrier();
    bi = (bi + 1 == 3) ? 0 : bi + 1;
  }
  if constexpr (NFR == 4) asm volatile("s_waitcnt vmcnt(4)" ::: "memory");
  else                    asm volatile("s_waitcnt vmcnt(3)" ::: "memory");
  __builtin_amdgcn_s_barrier();
  __builtin_amdgcn_sched_barrier(0);
  COMP(bi);
  asm volatile("s_waitcnt lgkmcnt(0)" ::: "memory");
  __builtin_amdgcn_s_barrier();
  bi = (bi + 1 == 3) ? 0 : bi + 1;
  asm volatile("s_waitcnt vmcnt(0)" ::: "memory");
  __builtin_amdgcn_s_barrier();
  __builtin_amdgcn_sched_barrier(0);
  COMP(bi);

  if constexpr (FUSED) {
    if (vpath) {
      // V: write transposed + chunk-permuted directly to vt[hd][l'].
      // l&31 = (m&1)*16 + g*4 + r  ->  slot pi^-1 = g*8 + (m&1)*4 + r
#pragma unroll
      for (int m = 0; m < 4; ++m) {
        const int lp = bm * 128 + wm * 64 + (m >> 1) * 32 + g * 8 + (m & 1) * 4;
#pragma unroll
        for (int n = 0; n < NFR; ++n) {
          const int col = bn * BN + wn * 16 * NFR + n * 16 + r16;   // 512..1023
          union { u16x4 v; unsigned wrd[2]; } o;
          o.wrd[0] = cvt_pk_bf16(acc[m][n][0], acc[m][n][1]);
          o.wrd[1] = cvt_pk_bf16(acc[m][n][2], acc[m][n][3]);
          *(u16x4*)&Cv[(size_t)(col - 512) * 2048 + lp] = o.v;
        }
      }
      return;
    }
  }

#pragma unroll
  for (int m = 0; m < 4; ++m) {
    const int row0 = bm * 128 + wm * 64 + m * 16 + g * 4;
#pragma unroll
    for (int n = 0; n < NFR; ++n) {
      const int col = bn * BN + wn * 16 * NFR + n * 16 + r16;
#pragma unroll
      for (int r = 0; r < 4; ++r) {
        if constexpr (OUTF32)
          ((float*)C)[(size_t)(row0 + r) * N + col] = acc[m][n][r];
        else
          ((u16*)C)[(size_t)(row0 + r) * N + col] = f2bf(acc[m][n][r]);
      }
    }
  }
}

// ---------- split-K=2 NT GEMM (O-proj), round-8 structure, f32 out ----------
// 1024 blocks: gl>=512 computes upper K half into the partial buffer.
template<int K, int NFR>
__global__ __launch_bounds__(256) void k_gemm_sk(const u16* __restrict__ A,
                                                 const u16* __restrict__ Bw,
                                                 float* __restrict__ C0,
                                                 float* __restrict__ C1p,
                                                 int N, int npx) {
  constexpr int BN = NFR * 32;
  constexpr int KLEN = K / 2;
  constexpr int nk = KLEN / 32;
  constexpr int LBB = BN / 64;
  __shared__ u16 As[3][128 * 32];
  __shared__ u16 Bs[3][BN * 32];
  const int t = threadIdx.x;
  const int lane = t & 63;
  const int w = t >> 6, wm = w >> 1, wn = w & 1;
  const int g = lane >> 4, r16 = lane & 15;
  const int bb = blockIdx.x;
  int gl = (bb & 7) * npx + (bb >> 3);         // XCD-contiguous mapping
  const int ks = gl >> 9; gl &= 511;           // 512 blocks per K-slice
  const int bm = gl & 15;
  const int bn = gl >> 4;
  float* C = ks ? C1p : C0;
  const u16* B  = Bw + (size_t)bn * BN * K + ks * KLEN;
  const u16* Ab = A  + (size_t)bm * 128 * K + ks * KLEN;

  f4 acc[4][NFR] = {};

  auto STAGE = [&](int kk, int bi) {
    const int k0 = kk * 32;
#pragma unroll
    for (int i2 = 0; i2 < 2; ++i2) {
      const int s = t + 256 * i2;
      const int row = s >> 2, slot = s & 3;
      gll16(Ab + (size_t)row * K + k0 + ((slot ^ (row & 3)) * 8), As[bi] + s * 8);
    }
#pragma unroll
    for (int i2 = 0; i2 < LBB; ++i2) {
      const int s = t + 256 * i2;
      const int col = s >> 2, slot = s & 3;
      gll16(B + (size_t)col * K + k0 + ((slot ^ (col & 3)) * 8), Bs[bi] + s * 8);
    }
  };
  auto COMP = [&](int bi) {
    bh8 af[4], bfr[NFR];
    const int x4 = g ^ (r16 & 3);
#pragma unroll
    for (int m = 0; m < 4; ++m)
      af[m] = *(const bh8*)&As[bi][((wm * 64 + m * 16 + r16) * 4 + x4) * 8];
#pragma unroll
    for (int n = 0; n < NFR; ++n)
      bfr[n] = *(const bh8*)&Bs[bi][((wn * 16 * NFR + n * 16 + r16) * 4 + x4) * 8];
    __builtin_amdgcn_s_setprio(1);
#pragma unroll
    for (int m = 0; m < 4; ++m)
#pragma unroll
      for (int n = 0; n < NFR; ++n)
        acc[m][n] = __builtin_amdgcn_mfma_f32_16x16x32_bf16(af[m], bfr[n], acc[m][n], 0, 0, 0);
    __builtin_amdgcn_s_setprio(0);
  };

  STAGE(0, 0);
  STAGE(1, 1);

  int bi = 0;
  for (int k = 0; k < nk - 2; ++k) {
    int st = bi + 2; if (st >= 3) st -= 3;
    STAGE(k + 2, st);
    asm volatile("s_waitcnt vmcnt(6)" ::: "memory");   // LPS=3, 2 stages in flight
    __builtin_amdgcn_s_barrier();
    __builtin_amdgcn_sched_barrier(0);
    COMP(bi);
    asm volatile("s_waitcnt lgkmcnt(0)" ::: "memory");
    __builtin_amdgcn_s_barrier();
    bi = (bi + 1 == 3) ? 0 : bi + 1;
  }
  asm volatile("s_waitcnt vmcnt(3)" ::: "memory");
  __builtin_amdgcn_s_barrier();
  __builtin_amdgcn_sched_barrier(0);
  COMP(bi);
  asm volatile("s_waitcnt lgkmcnt(0)" ::: "memory");
  __builtin_amdgcn_s_barrier();
  bi = (bi + 1 == 3) ? 0 : bi + 1;
  asm volatile("s_waitcnt vmcnt(0)" ::: "memory");
  __builtin_amdgcn_s_barrier();
  __builtin_amdgcn_sched_barrier(0);
  COMP(bi);

#pragma unroll
  for (int m = 0; m < 4; ++m) {
    const int row0 = bm * 128 + wm * 64 + m * 16 + g * 4;
#pragma unroll
    for (int n = 0; n < NFR; ++n) {
      const int col = bn * BN + wn * 16 * NFR + n * 16 + r16;
#pragma unroll
      for (int r = 0; r < 4; ++r)
        C[(size_t)(row0 + r) * N + col] = acc[m][n][r];
    }
  }
}

// ---------- split-K reduce: d_out += partial ----------
__global__ __launch_bounds__(256) void k_reduce(float* __restrict__ out,
                                                const float* __restrict__ part) {
  const size_t i = (size_t)blockIdx.x * 256 + threadIdx.x;   // f4 index, 1M total
  f4 a = *(const f4*)(out + i * 4);
  f4 b = *(const f4*)(part + i * 4);
  a += b;
  *(f4*)(out + i * 4) = a;
}

// ---------- fused RMSNorm + RoPE (in-place on bf16 Q / K buffers) ----------
__global__ __launch_bounds__(256) void k_normrope(u16* __restrict__ qbuf,
                                                  u16* __restrict__ kvbuf,
                                                  const float* __restrict__ qw,
                                                  const float* __restrict__ kw,
                                                  const float* __restrict__ cosb,
                                                  const float* __restrict__ sinb) {
  const float CSC = 1.4426950408889634f * 0.088388347648318447f;  // log2(e)/sqrt(128)
  const int t = threadIdx.x, lane = t & 63, w = t >> 6;
  const int rid = blockIdx.x * 4 + w;
  u16* base; const float* nw; int seq; float sc;
  if (rid < 2048 * 32) {
    seq = rid >> 5;
    base = qbuf + (size_t)seq * 4096 + (size_t)(rid & 31) * 128;
    nw = qw; sc = CSC;
  } else {
    const int r2 = rid - 2048 * 32;
    seq = r2 >> 2;
    base = kvbuf + (size_t)seq * 1024 + (size_t)(r2 & 3) * 128;
    nw = kw; sc = 1.0f;
  }
  float a = bf2f(base[lane]);
  float b = bf2f(base[lane + 64]);
  float ss = a * a + b * b;
#pragma unroll
  for (int off = 32; off >= 1; off >>= 1) ss += __shfl_xor(ss, off);
  const float rs = rsqrtf(ss * (1.0f / 128.0f) + 1e-6f);
  const float na = a * rs * nw[lane];
  const float nb = b * rs * nw[lane + 64];
  const float c1 = cosb[seq * 128 + lane],      s1 = sinb[seq * 128 + lane];
  const float c2 = cosb[seq * 128 + lane + 64], s2 = sinb[seq * 128 + lane + 64];
  base[lane]      = f2bf(sc * (c1 * na - s1 * nb));
  base[lane + 64] = f2bf(sc * (c2 * nb + s2 * na));
}

// ---------- flash attention (round-13 structure; only launch bounds changed) ----------
// 8 waves, 128 q-rows/block, KVBLK=64.  K dbuf + V single-buffered (48KB LDS).
// Grid 512, paired qt so each CU gets uniform 34 iterations.  Swapped QK^T
// (log2-domain scores); PV on x32 with chunk-permuted V^T; lsum via ones-MFMA.
// __launch_bounds__(512,6): cap VGPR ~85 so 3 blocks/CU fit (LDS 3x48=144KB OK).
__global__ __launch_bounds__(512, 6) void k_attn(const u16* __restrict__ Q,
                                                 const u16* __restrict__ Kb,
                                                 const u16* __restrict__ Vt,
                                                 u16* __restrict__ O) {
  __shared__ u16 Ks[2][64 * 128];   // 32 KB
  __shared__ u16 Vs[128 * 64];      // 16 KB
  const int t = threadIdx.x, lane = t & 63, w = t >> 6;   // w 0..7
  const int g = lane >> 4, r16 = lane & 15;
  const int b = blockIdx.x;
  const int i = b & 31;
  const int j = b >> 5;                                   // 0..15
  const int qt = (j < 8) ? (15 - j) : (j - 8);            // pair big+small per CU
  const int h = ((i >> 1) & 3) * 8 + ((i & 1) << 2) + (i >> 3);
  const int kvh = h >> 3;
  const int qw0 = qt * 128 + w * 16;
  const int qg  = qw0 + r16;

  bh8 qf[4];
#pragma unroll
  for (int kc = 0; kc < 4; ++kc)
    qf[kc] = *(const bh8*)(Q + (size_t)qg * 4096 + h * 128 + (kc * 4 + g) * 8);

  const int niter = 2 * qt + 2;

  f4 acc_o[8] = {};
  f4 acc_l = {};                     // lsum via ones-MFMA
  float mrun = -3.0e38f;

  bh8 ones;
#pragma unroll
  for (int z = 0; z < 8; ++z) ones[z] = (short)0x3F80;   // 1.0bf16

  // prologue: stage K[0] (16KB, 512 thr x 16B x 2 passes)
#pragma unroll
  for (int i2 = 0; i2 < 2; ++i2) {
    const int s = t + 512 * i2, row = s >> 4, sl = s & 15;
    gll16(Kb + (size_t)row * 1024 + kvh * 128 + ((sl ^ (row & 15)) * 8), Ks[0] + s * 8);
  }
  __syncthreads();

  int cur = 0;
  for (int kt = 0; kt < niter; ++kt) {
    // stage V[kt]; prefetch K[kt+1]
#pragma unroll
    for (int i2 = 0; i2 < 2; ++i2) {
      const int s = t + 512 * i2, row = s >> 3, sl = s & 7;
      gll16(Vt + (size_t)(kvh * 128 + row) * 2048 + kt * 64 + ((sl ^ (row & 7)) * 8),
            Vs + s * 8);
    }
    if (kt + 1 < niter) {
      const int nt = kt + 1;
#pragma unroll
      for (int i2 = 0; i2 < 2; ++i2) {
        const int s = t + 512 * i2, row = s >> 4, sl = s & 15;
        gll16(Kb + (size_t)(nt * 64 + row) * 1024 + kvh * 128 + ((sl ^ (row & 15)) * 8),
              Ks[cur ^ 1] + s * 8);
      }
    }

    // QK^T (swapped operands -> S^T), scores in log2 domain
    f4 st[4] = {};
    __builtin_amdgcn_s_setprio(1);
#pragma unroll
    for (int kf = 0; kf < 4; ++kf) {
      const int krow = kf * 16 + r16;
#pragma unroll
      for (int kc = 0; kc < 4; ++kc) {
        bh8 kfr = *(const bh8*)&Ks[cur][krow * 128 + (((kc * 4 + g) ^ (krow & 15)) * 8)];
        st[kf] = __builtin_amdgcn_mfma_f32_16x16x32_bf16(kfr, qf[kc], st[kf], 0, 0, 0);
      }
    }
    __builtin_amdgcn_s_setprio(0);

    // causal mask only on the last two k-tiles (block-uniform branch)
    if (kt >= 2 * qt) {
      const int kb = kt * 64 + g * 4;
#pragma unroll
      for (int kf = 0; kf < 4; ++kf)
#pragma unroll
        for (int r = 0; r < 4; ++r)
          if (kb + kf * 16 + r > qg) st[kf][r] = -3.0e38f;
    }

    // row max
    f4 m4;
#pragma unroll
    for (int r = 0; r < 4; ++r)
      m4[r] = fmaxf(fmaxf(st[0][r], st[1][r]), fmaxf(st[2][r], st[3][r]));
    float tmax = fmaxf(fmaxf(m4[0], m4[1]), fmaxf(m4[2], m4[3]));
    tmax = fmaxf(tmax, __shfl_xor(tmax, 16));
    tmax = fmaxf(tmax, __shfl_xor(tmax, 32));

    if (!__all(tmax <= mrun + 8.0f)) {       // defer-max (T13)
      const float mnew = fmaxf(mrun, tmax);
      const float alpha = fast_exp2(mrun - mnew);
      mrun = mnew;
      acc_l *= alpha;
#pragma unroll
      for (int d = 0; d < 8; ++d) acc_o[d] *= alpha;
    }

    // P = exp2(S - m), packed to bf16 via v_cvt_pk
    union { bh8 v[2]; unsigned wrd[8]; } pu;
#pragma unroll
    for (int j2 = 0; j2 < 8; ++j2) {
      const int i0 = 2 * j2, i1 = 2 * j2 + 1;
      float p0 = fast_exp2(st[i0 >> 2][i0 & 3] - mrun);
      float p1 = fast_exp2(st[i1 >> 2][i1 & 3] - mrun);
      pu.wrd[j2] = cvt_pk_bf16(p0, p1);
    }

    __syncthreads();   // V[kt] staged; all QK^T reads of Ks[cur] done

    // O^T += V^T * P^T ; lsum += ones * P^T
    __builtin_amdgcn_s_setprio(1);
#pragma unroll
    for (int c = 0; c < 2; ++c)
      acc_l = __builtin_amdgcn_mfma_f32_16x16x32_bf16(ones, pu.v[c], acc_l, 0, 0, 0);
#pragma unroll
    for (int dcol = 0; dcol < 8; ++dcol) {
      const int vrow = dcol * 16 + r16;
#pragma unroll
      for (int c = 0; c < 2; ++c) {
        const int slot = c * 4 + g;
        bh8 vfr = *(const bh8*)&Vs[vrow * 64 + ((slot ^ (vrow & 7)) * 8)];
        acc_o[dcol] = __builtin_amdgcn_mfma_f32_16x16x32_bf16(vfr, pu.v[c], acc_o[dcol], 0, 0, 0);
      }
    }
    __builtin_amdgcn_s_setprio(0);

    __syncthreads();   // PV reads of Vs done before next iter's V stage
    cur ^= 1;
  }

  const float inv = 1.0f / acc_l[0];
#pragma unroll
  for (int dcol = 0; dcol < 8; ++dcol) {
    union { u16x4 v; unsigned wrd[2]; } o;
    o.wrd[0] = cvt_pk_bf16(acc_o[dcol][0] * inv, acc_o[dcol][1] * inv);
    o.wrd[1] = cvt_pk_bf16(acc_o[dcol][2] * inv, acc_o[dcol][3] * inv);
    *(u16x4*)&O[(size_t)qg * 4096 + h * 128 + dcol * 16 + g * 4] = o.v;
  }
}

// ---------- launch ----------
extern "C" void kernel_launch(void* const* d_in, const int* in_sizes, int n_in,
                              void* d_out, int out_size, void* d_ws, size_t ws_size,
                              hipStream_t stream) {
  (void)in_sizes; (void)n_in; (void)out_size; (void)ws_size;
  const float* x    = (const float*)d_in[0];
  const float* wq   = (const float*)d_in[1];
  const float* wk   = (const float*)d_in[2];
  const float* wv   = (const float*)d_in[3];
  const float* wo   = (const float*)d_in[4];
  const float* qw   = (const float*)d_in[5];
  const float* kw   = (const float*)d_in[6];
  const float* cosb = (const float*)d_in[7];
  const float* sinb = (const float*)d_in[8];

  u16* xb   = (u16*)d_ws;                    // [2048][2048]
  u16* wqb  = xb  + (size_t)2048 * 2048;     // [4096][2048]  (reused as f32 partial after QKV)
  u16* wkvb = wqb + (size_t)4096 * 2048;     // [1024][2048]
  u16* wob  = wkvb + (size_t)1024 * 2048;    // [2048][4096]
  u16* qbuf = wob + (size_t)2048 * 4096;     // [2048][4096]
  u16* kvb  = qbuf + (size_t)2048 * 4096;    // [2048][1024]  (K cols 0..511)
  u16* vt   = kvb + (size_t)2048 * 1024;     // [512][2048]   V^T (chunk-permuted)
  u16* aout = vt  + (size_t)512 * 2048;      // [2048][4096]
  float* partial = (float*)wqb;              // 2048*2048 f32 = 16MB, fits wqb region

  // 1. fused converts
  k_cvt_all<<<dim3(4096), 256, 0, stream>>>(x, wq, wk, wv, wo, xb);

  // 2. fused Q + KV projection (round-11 config: NFR=4, 640 blocks)
  k_gemm<2048, false, 4, true><<<dim3(640), 256, 0, stream>>>(
      xb, wqb, wkvb, qbuf, kvb, vt, 4096, 1024, 32, 80, 4);

  // 3. rmsnorm + rope (+ Q pre-scale)
  k_normrope<<<dim3((2048 * 36) / 4), 256, 0, stream>>>(qbuf, kvb, qw, kw, cosb, sinb);

  // 4. flash attention (512 paired 8-wave blocks, 3 blocks/CU target)
  k_attn<<<dim3(512), 512, 0, stream>>>(qbuf, kvb, vt, aout);

  // 5. output projection, split-K=2 with round-8 pipeline structure
  k_gemm_sk<4096, 2><<<dim3(1024), 256, 0, stream>>>(
      aout, wob, (float*)d_out, partial, 2048, 128);

  // 6. reduce partial into d_out
  k_reduce<<<dim3(4096), 256, 0, stream>>>((float*)d_out, partial);
}

// Round 16
// 197.192 us; speedup vs baseline: 1.4603x; 1.4603x over previous
//
#include <hip/hip_runtime.h>

typedef unsigned short u16;
typedef short bh8 __attribute__((ext_vector_type(8)));
typedef short bh4 __attribute__((ext_vector_type(4)));
typedef float f4 __attribute__((ext_vector_type(4)));
typedef u16 u16x4 __attribute__((ext_vector_type(4)));

// ---------- helpers ----------
__device__ __forceinline__ u16 f2bf(float f) {
  union { float f; unsigned u; } v; v.f = f;
  unsigned u = v.u;
  return (u16)((u + 0x7fffu + ((u >> 16) & 1u)) >> 16);   // RNE, finite inputs
}
__device__ __forceinline__ float bf2f(u16 h) {
  union { unsigned u; float f; } v; v.u = ((unsigned)h) << 16;
  return v.f;
}
__device__ __forceinline__ float fast_exp2(float x) {
#if __has_builtin(__builtin_amdgcn_exp2f)
  return __builtin_amdgcn_exp2f(x);
#else
  float r; asm("v_exp_f32 %0, %1" : "=v"(r) : "v"(x)); return r;
#endif
}
__device__ __forceinline__ unsigned cvt_pk_bf16(float lo, float hi) {
  unsigned r;
  asm("v_cvt_pk_bf16_f32 %0, %1, %2" : "=v"(r) : "v"(lo), "v"(hi));
  return r;
}
__device__ __forceinline__ void gll16(const void* src, void* dst) {
  __builtin_amdgcn_global_load_lds((const __attribute__((address_space(1))) void*)src,
                                   (__attribute__((address_space(3))) void*)dst,
                                   16, 0, 0);
}

// ---------- fused f32 -> bf16 convert of all 5 tensors (contiguous ws dst) ----------
__global__ __launch_bounds__(256) void k_cvt_all(const float* __restrict__ x,
                                                 const float* __restrict__ wq,
                                                 const float* __restrict__ wk,
                                                 const float* __restrict__ wv,
                                                 const float* __restrict__ wo,
                                                 u16* __restrict__ dst) {
  const size_t n = 5767168;   // total float4 count
  for (size_t idx = (size_t)blockIdx.x * 256 + threadIdx.x; idx < n; idx += 4096ull * 256) {
    const float* src; size_t off;
    if (idx < 1048576)       { src = x;  off = idx; }
    else if (idx < 3145728)  { src = wq; off = idx - 1048576; }
    else if (idx < 3407872)  { src = wk; off = idx - 3145728; }
    else if (idx < 3670016)  { src = wv; off = idx - 3407872; }
    else                     { src = wo; off = idx - 3670016; }
    f4 v = *(const f4*)(src + off * 4);
    u16x4 o;
    o.x = f2bf(v[0]); o.y = f2bf(v[1]); o.z = f2bf(v[2]); o.w = f2bf(v[3]);
    *(u16x4*)(dst + idx * 4) = o;
  }
}

// ---------- NT GEMM, round-8 structure: straight-line main loop + hardcoded tail ----------
// C[M,N] = A[M,K] * B[N,K]^T.  128xBN tile (BN = NFR*32), BK=32, 4 waves (2x2).
// 3 LDS buffers, compile-time vmcnt (8/4/0 for NFR=4; 6/3/0 for NFR=2).
// XCD-contiguous 1D grid.  FUSED: bn<NB1 -> Q (C1); else KV: local bn<nbK -> K
// cols of C2; bn>=nbK -> V, written TRANSPOSED + chunk-permuted to Cv.
template<int K, bool OUTF32, int NFR, bool FUSED>
__global__ __launch_bounds__(256) void k_gemm(const u16* __restrict__ A,
                                              const u16* __restrict__ B1,
                                              const u16* __restrict__ B2,
                                              void* __restrict__ C1,
                                              void* __restrict__ C2,
                                              u16* __restrict__ Cv,
                                              int N1, int N2, int NB1, int npx,
                                              int nbK) {
  constexpr int BN = NFR * 32;
  constexpr int nk = K / 32;
  constexpr int LBB = BN / 64;                 // B-staging loops (A has 2)
  __shared__ u16 As[3][128 * 32];
  __shared__ u16 Bs[3][BN * 32];
  const int t = threadIdx.x;
  const int lane = t & 63;
  const int w = t >> 6, wm = w >> 1, wn = w & 1;
  const int g = lane >> 4, r16 = lane & 15;
  const int bb = blockIdx.x;
  const int gl = (bb & 7) * npx + (bb >> 3);   // XCD-contiguous mapping
  const int bm = gl & 15;
  int bn = gl >> 4;

  const u16* B; void* C; int N; bool vpath = false;
  if (!FUSED || bn < NB1) { B = B1; C = C1; N = N1; }
  else { bn -= NB1; B = B2; C = C2; N = N2; vpath = (bn >= nbK); }
  B += (size_t)bn * BN * K;
  const u16* Ab = A + (size_t)bm * 128 * K;

  f4 acc[4][NFR] = {};

  auto STAGE = [&](int kk, int bi) {
    const int k0 = kk * 32;
#pragma unroll
    for (int i2 = 0; i2 < 2; ++i2) {
      const int s = t + 256 * i2;
      const int row = s >> 2, slot = s & 3;
      gll16(Ab + (size_t)row * K + k0 + ((slot ^ (row & 3)) * 8), As[bi] + s * 8);
    }
#pragma unroll
    for (int i2 = 0; i2 < LBB; ++i2) {
      const int s = t + 256 * i2;
      const int col = s >> 2, slot = s & 3;
      gll16(B + (size_t)col * K + k0 + ((slot ^ (col & 3)) * 8), Bs[bi] + s * 8);
    }
  };
  auto COMP = [&](int bi) {
    bh8 af[4], bfr[NFR];
    const int x4 = g ^ (r16 & 3);              // row&3 == col&3 == r16&3
#pragma unroll
    for (int m = 0; m < 4; ++m)
      af[m] = *(const bh8*)&As[bi][((wm * 64 + m * 16 + r16) * 4 + x4) * 8];
#pragma unroll
    for (int n = 0; n < NFR; ++n)
      bfr[n] = *(const bh8*)&Bs[bi][((wn * 16 * NFR + n * 16 + r16) * 4 + x4) * 8];
    __builtin_amdgcn_s_setprio(1);
#pragma unroll
    for (int m = 0; m < 4; ++m)
#pragma unroll
      for (int n = 0; n < NFR; ++n)
        acc[m][n] = __builtin_amdgcn_mfma_f32_16x16x32_bf16(af[m], bfr[n], acc[m][n], 0, 0, 0);
    __builtin_amdgcn_s_setprio(0);
  };

  STAGE(0, 0);
  STAGE(1, 1);

  int bi = 0;
  for (int k = 0; k < nk - 2; ++k) {
    int st = bi + 2; if (st >= 3) st -= 3;
    STAGE(k + 2, st);
    if constexpr (NFR == 4) asm volatile("s_waitcnt vmcnt(8)" ::: "memory");
    else                    asm volatile("s_waitcnt vmcnt(6)" ::: "memory");
    __builtin_amdgcn_s_barrier();
    __builtin_amdgcn_sched_barrier(0);
    COMP(bi);
    asm volatile("s_waitcnt lgkmcnt(0)" ::: "memory");
    __builtin_amdgcn_s_barrier();
    bi = (bi + 1 == 3) ? 0 : bi + 1;
  }
  if constexpr (NFR == 4) asm volatile("s_waitcnt vmcnt(4)" ::: "memory");
  else                    asm volatile("s_waitcnt vmcnt(3)" ::: "memory");
  __builtin_amdgcn_s_barrier();
  __builtin_amdgcn_sched_barrier(0);
  COMP(bi);
  asm volatile("s_waitcnt lgkmcnt(0)" ::: "memory");
  __builtin_amdgcn_s_barrier();
  bi = (bi + 1 == 3) ? 0 : bi + 1;
  asm volatile("s_waitcnt vmcnt(0)" ::: "memory");
  __builtin_amdgcn_s_barrier();
  __builtin_amdgcn_sched_barrier(0);
  COMP(bi);

  if constexpr (FUSED) {
    if (vpath) {
      // V: write transposed + chunk-permuted directly to vt[hd][l'].
      // l&31 = (m&1)*16 + g*4 + r  ->  slot pi^-1 = g*8 + (m&1)*4 + r
#pragma unroll
      for (int m = 0; m < 4; ++m) {
        const int lp = bm * 128 + wm * 64 + (m >> 1) * 32 + g * 8 + (m & 1) * 4;
#pragma unroll
        for (int n = 0; n < NFR; ++n) {
          const int col = bn * BN + wn * 16 * NFR + n * 16 + r16;   // 512..1023
          union { u16x4 v; unsigned wrd[2]; } o;
          o.wrd[0] = cvt_pk_bf16(acc[m][n][0], acc[m][n][1]);
          o.wrd[1] = cvt_pk_bf16(acc[m][n][2], acc[m][n][3]);
          *(u16x4*)&Cv[(size_t)(col - 512) * 2048 + lp] = o.v;
        }
      }
      return;
    }
  }

#pragma unroll
  for (int m = 0; m < 4; ++m) {
    const int row0 = bm * 128 + wm * 64 + m * 16 + g * 4;
#pragma unroll
    for (int n = 0; n < NFR; ++n) {
      const int col = bn * BN + wn * 16 * NFR + n * 16 + r16;
#pragma unroll
      for (int r = 0; r < 4; ++r) {
        if constexpr (OUTF32)
          ((float*)C)[(size_t)(row0 + r) * N + col] = acc[m][n][r];
        else
          ((u16*)C)[(size_t)(row0 + r) * N + col] = f2bf(acc[m][n][r]);
      }
    }
  }
}

// ---------- split-K=2 NT GEMM (O-proj), round-8 structure, f32 out ----------
// 1024 blocks: gl>=512 computes upper K half into the partial buffer.
template<int K, int NFR>
__global__ __launch_bounds__(256) void k_gemm_sk(const u16* __restrict__ A,
                                                 const u16* __restrict__ Bw,
                                                 float* __restrict__ C0,
                                                 float* __restrict__ C1p,
                                                 int N, int npx) {
  constexpr int BN = NFR * 32;
  constexpr int KLEN = K / 2;
  constexpr int nk = KLEN / 32;
  constexpr int LBB = BN / 64;
  __shared__ u16 As[3][128 * 32];
  __shared__ u16 Bs[3][BN * 32];
  const int t = threadIdx.x;
  const int lane = t & 63;
  const int w = t >> 6, wm = w >> 1, wn = w & 1;
  const int g = lane >> 4, r16 = lane & 15;
  const int bb = blockIdx.x;
  int gl = (bb & 7) * npx + (bb >> 3);         // XCD-contiguous mapping
  const int ks = gl >> 9; gl &= 511;           // 512 blocks per K-slice
  const int bm = gl & 15;
  const int bn = gl >> 4;
  float* C = ks ? C1p : C0;
  const u16* B  = Bw + (size_t)bn * BN * K + ks * KLEN;
  const u16* Ab = A  + (size_t)bm * 128 * K + ks * KLEN;

  f4 acc[4][NFR] = {};

  auto STAGE = [&](int kk, int bi) {
    const int k0 = kk * 32;
#pragma unroll
    for (int i2 = 0; i2 < 2; ++i2) {
      const int s = t + 256 * i2;
      const int row = s >> 2, slot = s & 3;
      gll16(Ab + (size_t)row * K + k0 + ((slot ^ (row & 3)) * 8), As[bi] + s * 8);
    }
#pragma unroll
    for (int i2 = 0; i2 < LBB; ++i2) {
      const int s = t + 256 * i2;
      const int col = s >> 2, slot = s & 3;
      gll16(B + (size_t)col * K + k0 + ((slot ^ (col & 3)) * 8), Bs[bi] + s * 8);
    }
  };
  auto COMP = [&](int bi) {
    bh8 af[4], bfr[NFR];
    const int x4 = g ^ (r16 & 3);
#pragma unroll
    for (int m = 0; m < 4; ++m)
      af[m] = *(const bh8*)&As[bi][((wm * 64 + m * 16 + r16) * 4 + x4) * 8];
#pragma unroll
    for (int n = 0; n < NFR; ++n)
      bfr[n] = *(const bh8*)&Bs[bi][((wn * 16 * NFR + n * 16 + r16) * 4 + x4) * 8];
    __builtin_amdgcn_s_setprio(1);
#pragma unroll
    for (int m = 0; m < 4; ++m)
#pragma unroll
      for (int n = 0; n < NFR; ++n)
        acc[m][n] = __builtin_amdgcn_mfma_f32_16x16x32_bf16(af[m], bfr[n], acc[m][n], 0, 0, 0);
    __builtin_amdgcn_s_setprio(0);
  };

  STAGE(0, 0);
  STAGE(1, 1);

  int bi = 0;
  for (int k = 0; k < nk - 2; ++k) {
    int st = bi + 2; if (st >= 3) st -= 3;
    STAGE(k + 2, st);
    asm volatile("s_waitcnt vmcnt(6)" ::: "memory");   // LPS=3, 2 stages in flight
    __builtin_amdgcn_s_barrier();
    __builtin_amdgcn_sched_barrier(0);
    COMP(bi);
    asm volatile("s_waitcnt lgkmcnt(0)" ::: "memory");
    __builtin_amdgcn_s_barrier();
    bi = (bi + 1 == 3) ? 0 : bi + 1;
  }
  asm volatile("s_waitcnt vmcnt(3)" ::: "memory");
  __builtin_amdgcn_s_barrier();
  __builtin_amdgcn_sched_barrier(0);
  COMP(bi);
  asm volatile("s_waitcnt lgkmcnt(0)" ::: "memory");
  __builtin_amdgcn_s_barrier();
  bi = (bi + 1 == 3) ? 0 : bi + 1;
  asm volatile("s_waitcnt vmcnt(0)" ::: "memory");
  __builtin_amdgcn_s_barrier();
  __builtin_amdgcn_sched_barrier(0);
  COMP(bi);

#pragma unroll
  for (int m = 0; m < 4; ++m) {
    const int row0 = bm * 128 + wm * 64 + m * 16 + g * 4;
#pragma unroll
    for (int n = 0; n < NFR; ++n) {
      const int col = bn * BN + wn * 16 * NFR + n * 16 + r16;
#pragma unroll
      for (int r = 0; r < 4; ++r)
        C[(size_t)(row0 + r) * N + col] = acc[m][n][r];
    }
  }
}

// ---------- split-K reduce: d_out += partial ----------
__global__ __launch_bounds__(256) void k_reduce(float* __restrict__ out,
                                                const float* __restrict__ part) {
  const size_t i = (size_t)blockIdx.x * 256 + threadIdx.x;   // f4 index, 1M total
  f4 a = *(const f4*)(out + i * 4);
  f4 b = *(const f4*)(part + i * 4);
  a += b;
  *(f4*)(out + i * 4) = a;
}

// ---------- fused RMSNorm + RoPE (in-place on bf16 Q / K buffers) ----------
__global__ __launch_bounds__(256) void k_normrope(u16* __restrict__ qbuf,
                                                  u16* __restrict__ kvbuf,
                                                  const float* __restrict__ qw,
                                                  const float* __restrict__ kw,
                                                  const float* __restrict__ cosb,
                                                  const float* __restrict__ sinb) {
  const float CSC = 1.4426950408889634f * 0.088388347648318447f;  // log2(e)/sqrt(128)
  const int t = threadIdx.x, lane = t & 63, w = t >> 6;
  const int rid = blockIdx.x * 4 + w;
  u16* base; const float* nw; int seq; float sc;
  if (rid < 2048 * 32) {
    seq = rid >> 5;
    base = qbuf + (size_t)seq * 4096 + (size_t)(rid & 31) * 128;
    nw = qw; sc = CSC;
  } else {
    const int r2 = rid - 2048 * 32;
    seq = r2 >> 2;
    base = kvbuf + (size_t)seq * 1024 + (size_t)(r2 & 3) * 128;
    nw = kw; sc = 1.0f;
  }
  float a = bf2f(base[lane]);
  float b = bf2f(base[lane + 64]);
  float ss = a * a + b * b;
#pragma unroll
  for (int off = 32; off >= 1; off >>= 1) ss += __shfl_xor(ss, off);
  const float rs = rsqrtf(ss * (1.0f / 128.0f) + 1e-6f);
  const float na = a * rs * nw[lane];
  const float nb = b * rs * nw[lane + 64];
  const float c1 = cosb[seq * 128 + lane],      s1 = sinb[seq * 128 + lane];
  const float c2 = cosb[seq * 128 + lane + 64], s2 = sinb[seq * 128 + lane + 64];
  base[lane]      = f2bf(sc * (c1 * na - s1 * nb));
  base[lane + 64] = f2bf(sc * (c2 * nb + s2 * na));
}

// ---------- flash attention (round-13 champion, verbatim) ----------
// 8 waves, 128 q-rows/block, KVBLK=64.  K dbuf + V single-buffered (48KB LDS).
// Grid 512, paired qt so each CU gets uniform 34 iterations.  Swapped QK^T
// (log2-domain scores); PV on x32 with chunk-permuted V^T; lsum via ones-MFMA.
__global__ __launch_bounds__(512, 4) void k_attn(const u16* __restrict__ Q,
                                                 const u16* __restrict__ Kb,
                                                 const u16* __restrict__ Vt,
                                                 u16* __restrict__ O) {
  __shared__ u16 Ks[2][64 * 128];   // 32 KB
  __shared__ u16 Vs[128 * 64];      // 16 KB
  const int t = threadIdx.x, lane = t & 63, w = t >> 6;   // w 0..7
  const int g = lane >> 4, r16 = lane & 15;
  const int b = blockIdx.x;
  const int i = b & 31;
  const int j = b >> 5;                                   // 0..15
  const int qt = (j < 8) ? (15 - j) : (j - 8);            // pair big+small per CU
  const int h = ((i >> 1) & 3) * 8 + ((i & 1) << 2) + (i >> 3);
  const int kvh = h >> 3;
  const int qw0 = qt * 128 + w * 16;
  const int qg  = qw0 + r16;

  bh8 qf[4];
#pragma unroll
  for (int kc = 0; kc < 4; ++kc)
    qf[kc] = *(const bh8*)(Q + (size_t)qg * 4096 + h * 128 + (kc * 4 + g) * 8);

  const int niter = 2 * qt + 2;

  f4 acc_o[8] = {};
  f4 acc_l = {};                     // lsum via ones-MFMA
  float mrun = -3.0e38f;

  bh8 ones;
#pragma unroll
  for (int z = 0; z < 8; ++z) ones[z] = (short)0x3F80;   // 1.0bf16

  // prologue: stage K[0] (16KB, 512 thr x 16B x 2 passes)
#pragma unroll
  for (int i2 = 0; i2 < 2; ++i2) {
    const int s = t + 512 * i2, row = s >> 4, sl = s & 15;
    gll16(Kb + (size_t)row * 1024 + kvh * 128 + ((sl ^ (row & 15)) * 8), Ks[0] + s * 8);
  }
  __syncthreads();

  int cur = 0;
  for (int kt = 0; kt < niter; ++kt) {
    // stage V[kt]; prefetch K[kt+1]
#pragma unroll
    for (int i2 = 0; i2 < 2; ++i2) {
      const int s = t + 512 * i2, row = s >> 3, sl = s & 7;
      gll16(Vt + (size_t)(kvh * 128 + row) * 2048 + kt * 64 + ((sl ^ (row & 7)) * 8),
            Vs + s * 8);
    }
    if (kt + 1 < niter) {
      const int nt = kt + 1;
#pragma unroll
      for (int i2 = 0; i2 < 2; ++i2) {
        const int s = t + 512 * i2, row = s >> 4, sl = s & 15;
        gll16(Kb + (size_t)(nt * 64 + row) * 1024 + kvh * 128 + ((sl ^ (row & 15)) * 8),
              Ks[cur ^ 1] + s * 8);
      }
    }

    // QK^T (swapped operands -> S^T), scores in log2 domain
    f4 st[4] = {};
    __builtin_amdgcn_s_setprio(1);
#pragma unroll
    for (int kf = 0; kf < 4; ++kf) {
      const int krow = kf * 16 + r16;
#pragma unroll
      for (int kc = 0; kc < 4; ++kc) {
        bh8 kfr = *(const bh8*)&Ks[cur][krow * 128 + (((kc * 4 + g) ^ (krow & 15)) * 8)];
        st[kf] = __builtin_amdgcn_mfma_f32_16x16x32_bf16(kfr, qf[kc], st[kf], 0, 0, 0);
      }
    }
    __builtin_amdgcn_s_setprio(0);

    // causal mask only on the last two k-tiles (block-uniform branch)
    if (kt >= 2 * qt) {
      const int kb = kt * 64 + g * 4;
#pragma unroll
      for (int kf = 0; kf < 4; ++kf)
#pragma unroll
        for (int r = 0; r < 4; ++r)
          if (kb + kf * 16 + r > qg) st[kf][r] = -3.0e38f;
    }

    // row max
    f4 m4;
#pragma unroll
    for (int r = 0; r < 4; ++r)
      m4[r] = fmaxf(fmaxf(st[0][r], st[1][r]), fmaxf(st[2][r], st[3][r]));
    float tmax = fmaxf(fmaxf(m4[0], m4[1]), fmaxf(m4[2], m4[3]));
    tmax = fmaxf(tmax, __shfl_xor(tmax, 16));
    tmax = fmaxf(tmax, __shfl_xor(tmax, 32));

    if (!__all(tmax <= mrun + 8.0f)) {       // defer-max (T13)
      const float mnew = fmaxf(mrun, tmax);
      const float alpha = fast_exp2(mrun - mnew);
      mrun = mnew;
      acc_l *= alpha;
#pragma unroll
      for (int d = 0; d < 8; ++d) acc_o[d] *= alpha;
    }

    // P = exp2(S - m), packed to bf16 via v_cvt_pk
    union { bh8 v[2]; unsigned wrd[8]; } pu;
#pragma unroll
    for (int j2 = 0; j2 < 8; ++j2) {
      const int i0 = 2 * j2, i1 = 2 * j2 + 1;
      float p0 = fast_exp2(st[i0 >> 2][i0 & 3] - mrun);
      float p1 = fast_exp2(st[i1 >> 2][i1 & 3] - mrun);
      pu.wrd[j2] = cvt_pk_bf16(p0, p1);
    }

    __syncthreads();   // V[kt] staged; all QK^T reads of Ks[cur] done

    // O^T += V^T * P^T ; lsum += ones * P^T
    __builtin_amdgcn_s_setprio(1);
#pragma unroll
    for (int c = 0; c < 2; ++c)
      acc_l = __builtin_amdgcn_mfma_f32_16x16x32_bf16(ones, pu.v[c], acc_l, 0, 0, 0);
#pragma unroll
    for (int dcol = 0; dcol < 8; ++dcol) {
      const int vrow = dcol * 16 + r16;
#pragma unroll
      for (int c = 0; c < 2; ++c) {
        const int slot = c * 4 + g;
        bh8 vfr = *(const bh8*)&Vs[vrow * 64 + ((slot ^ (vrow & 7)) * 8)];
        acc_o[dcol] = __builtin_amdgcn_mfma_f32_16x16x32_bf16(vfr, pu.v[c], acc_o[dcol], 0, 0, 0);
      }
    }
    __builtin_amdgcn_s_setprio(0);

    __syncthreads();   // PV reads of Vs done before next iter's V stage
    cur ^= 1;
  }

  const float inv = 1.0f / acc_l[0];
#pragma unroll
  for (int dcol = 0; dcol < 8; ++dcol) {
    union { u16x4 v; unsigned wrd[2]; } o;
    o.wrd[0] = cvt_pk_bf16(acc_o[dcol][0] * inv, acc_o[dcol][1] * inv);
    o.wrd[1] = cvt_pk_bf16(acc_o[dcol][2] * inv, acc_o[dcol][3] * inv);
    *(u16x4*)&O[(size_t)qg * 4096 + h * 128 + dcol * 16 + g * 4] = o.v;
  }
}

// ---------- launch ----------
extern "C" void kernel_launch(void* const* d_in, const int* in_sizes, int n_in,
                              void* d_out, int out_size, void* d_ws, size_t ws_size,
                              hipStream_t stream) {
  (void)in_sizes; (void)n_in; (void)out_size; (void)ws_size;
  const float* x    = (const float*)d_in[0];
  const float* wq   = (const float*)d_in[1];
  const float* wk   = (const float*)d_in[2];
  const float* wv   = (const float*)d_in[3];
  const float* wo   = (const float*)d_in[4];
  const float* qw   = (const float*)d_in[5];
  const float* kw   = (const float*)d_in[6];
  const float* cosb = (const float*)d_in[7];
  const float* sinb = (const float*)d_in[8];

  u16* xb   = (u16*)d_ws;                    // [2048][2048]
  u16* wqb  = xb  + (size_t)2048 * 2048;     // [4096][2048]  (reused as f32 partial after QKV)
  u16* wkvb = wqb + (size_t)4096 * 2048;     // [1024][2048]
  u16* wob  = wkvb + (size_t)1024 * 2048;    // [2048][4096]
  u16* qbuf = wob + (size_t)2048 * 4096;     // [2048][4096]
  u16* kvb  = qbuf + (size_t)2048 * 4096;    // [2048][1024]  (K cols 0..511)
  u16* vt   = kvb + (size_t)2048 * 1024;     // [512][2048]   V^T (chunk-permuted)
  u16* aout = vt  + (size_t)512 * 2048;      // [2048][4096]
  float* partial = (float*)wqb;              // 2048*2048 f32 = 16MB, fits wqb region

  // 1. fused converts
  k_cvt_all<<<dim3(4096), 256, 0, stream>>>(x, wq, wk, wv, wo, xb);

  // 2. fused Q + KV projection (round-11 config: NFR=4, 640 blocks)
  k_gemm<2048, false, 4, true><<<dim3(640), 256, 0, stream>>>(
      xb, wqb, wkvb, qbuf, kvb, vt, 4096, 1024, 32, 80, 4);

  // 3. rmsnorm + rope (+ Q pre-scale)
  k_normrope<<<dim3((2048 * 36) / 4), 256, 0, stream>>>(qbuf, kvb, qw, kw, cosb, sinb);

  // 4. flash attention (512 paired 8-wave blocks)
  k_attn<<<dim3(512), 512, 0, stream>>>(qbuf, kvb, vt, aout);

  // 5. output projection, split-K=2 with round-8 pipeline structure
  k_gemm_sk<4096, 2><<<dim3(1024), 256, 0, stream>>>(
      aout, wob, (float*)d_out, partial, 2048, 128);

  // 6. reduce partial into d_out
  k_reduce<<<dim3(4096), 256, 0, stream>>>((float*)d_out, partial);
}